// Round 12
// baseline (200.328 us; speedup 1.0000x reference)
//
#include <hip/hip_runtime.h>
#include <hip/hip_bf16.h>

#define B_  2
#define S_  2048
#define H_  1024
#define NH_ 16
#define HD_ 64
#define EPSLN 1e-12f
#define LOG2E 1.4426950408889634f

typedef short bf16x8 __attribute__((ext_vector_type(8)));
typedef float f32x4  __attribute__((ext_vector_type(4)));
typedef float f32x16 __attribute__((ext_vector_type(16)));
typedef unsigned int u32x4 __attribute__((ext_vector_type(4)));

__device__ __forceinline__ float bf2f(ushort u) {
    union { unsigned int i; float f; } v; v.i = ((unsigned int)u) << 16; return v.f;
}
__device__ __forceinline__ ushort f2bf(float f) {
    union { float f; unsigned int i; } v; v.f = f;
    unsigned int r = v.i + 0x7FFFu + ((v.i >> 16) & 1u);   // RNE
    return (ushort)(r >> 16);
}
__device__ __forceinline__ ushort f2bf_hw(float f) {
    __hip_bfloat16 h = __float2bfloat16(f);
    return *reinterpret_cast<ushort*>(&h);
}
__device__ __forceinline__ unsigned int pack_bf2(float a, float b) {
    return ((unsigned int)f2bf_hw(b) << 16) | (unsigned int)f2bf_hw(a);
}

// build one PV B-frag from 8 exp values (all by value -> registers only)
__device__ __forceinline__ bf16x8 mk_pfrag(float a0, float a1, float a2, float a3,
                                           float a4, float a5, float a6, float a7, int hi) {
    unsigned int Lo0 = pack_bf2(a0, a1);
    unsigned int Lo1 = pack_bf2(a2, a3);
    unsigned int Hi0 = pack_bf2(a4, a5);
    unsigned int Hi1 = pack_bf2(a6, a7);
    unsigned int sLo0 = (unsigned int)__shfl_xor((int)Lo0, 32, 64);
    unsigned int sLo1 = (unsigned int)__shfl_xor((int)Lo1, 32, 64);
    unsigned int sHi0 = (unsigned int)__shfl_xor((int)Hi0, 32, 64);
    unsigned int sHi1 = (unsigned int)__shfl_xor((int)Hi1, 32, 64);
    u32x4 d;
    d.x = hi ? sHi0 : Lo0;
    d.y = hi ? sHi1 : Lo1;
    d.z = hi ? Hi0 : sLo0;
    d.w = hi ? Hi1 : sLo1;
    return __builtin_bit_cast(bf16x8, d);
}

// ---------------------------------------------------------------- fp32 -> bf16 convert
__global__ __launch_bounds__(256) void cvt_f32_bf16(const float* __restrict__ in,
                                                    ushort* __restrict__ out, int n) {
    int i = (blockIdx.x * 256 + threadIdx.x) * 4;
    float4 v = *(const float4*)&in[i];
    ushort4 o = make_ushort4(f2bf(v.x), f2bf(v.y), f2bf(v.z), f2bf(v.w));
    *(ushort4*)&out[i] = o;
}

// ---------------------------------------------------------------- mask * log2(e)
__global__ __launch_bounds__(256) void scale_mask(const float* __restrict__ in,
                                                  float* __restrict__ out) {
    int i = blockIdx.x * 256 + threadIdx.x;
    out[i] = in[i] * LOG2E;
}

// ---------------------------------------------------------------- transpose + convert
__global__ __launch_bounds__(256) void transpose_cvt(
        const float* __restrict__ W0, const float* __restrict__ W1,
        const float* __restrict__ W2, const float* __restrict__ W3,
        ushort* __restrict__ T0, ushort* __restrict__ T1,
        ushort* __restrict__ T2, ushort* __restrict__ T3) {
    const int z = blockIdx.z;
    const float* in = (z == 0) ? W0 : (z == 1) ? W1 : (z == 2) ? W2 : W3;
    ushort* out     = (z == 0) ? T0 : (z == 1) ? T1 : (z == 2) ? T2 : T3;

    __shared__ float tile[64][65];
    const int bx = blockIdx.x * 64, by = blockIdx.y * 64;
    const int t = threadIdx.x;
    #pragma unroll
    for (int i = 0; i < 16; i++) {
        int idx = t + i * 256;
        int r = idx >> 6, c = idx & 63;
        tile[r][c] = in[(by + r) * 1024 + bx + c];
    }
    __syncthreads();
    #pragma unroll
    for (int i = 0; i < 16; i++) {
        int idx = t + i * 256;
        int r = idx >> 6, c = idx & 63;
        out[(bx + r) * 1024 + by + c] = f2bf(tile[c][r]);
    }
}

// ---------------------------------------------------------------- V transpose (bf16)
__global__ __launch_bounds__(256) void v_transpose(const ushort* __restrict__ Vb,
                                                   ushort* __restrict__ VtG) {
    __shared__ ushort tile[64][72];
    const int s0 = blockIdx.x * 64;
    const int head = blockIdx.y;
    const ushort* src = Vb + (size_t)head * S_ * HD_;
    ushort* dst       = VtG + (size_t)head * S_ * HD_;
    const int t = threadIdx.x, lane = t & 63, w = t >> 6;

    uint4 a = *(const uint4*)&src[(s0 + lane) * HD_ + w * 16];
    uint4 b = *(const uint4*)&src[(s0 + lane) * HD_ + w * 16 + 8];
    const ushort* pa = (const ushort*)&a;
    #pragma unroll
    for (int i = 0; i < 8; i++) tile[w * 16 + i][lane] = pa[i];
    const ushort* pb = (const ushort*)&b;
    #pragma unroll
    for (int i = 0; i < 8; i++) tile[w * 16 + 8 + i][lane] = pb[i];
    __syncthreads();

    const int d = t >> 2, sc = (t & 3) * 16;
    uint4 o1 = *(const uint4*)&tile[d][sc];
    uint4 o2 = *(const uint4*)&tile[d][sc + 8];
    *(uint4*)&dst[d * S_ + s0 + sc]     = o1;
    *(uint4*)&dst[d * S_ + s0 + sc + 8] = o2;
}

// ---------------------------------------------------------------- QKV GEMM
__global__ __launch_bounds__(256) void qkv_gemm(
        const ushort* __restrict__ X,
        const ushort* __restrict__ Wqt, const ushort* __restrict__ Wkt, const ushort* __restrict__ Wvt,
        const float* __restrict__ bq,  const float* __restrict__ bk,  const float* __restrict__ bv,
        ushort* __restrict__ Qo, ushort* __restrict__ Ko, ushort* __restrict__ Vo) {
    const int which = blockIdx.z;
    const ushort* Wt  = (which == 0) ? Wqt : (which == 1) ? Wkt : Wvt;
    const float* bias = (which == 0) ? bq  : (which == 1) ? bk  : bv;
    ushort* Out       = (which == 0) ? Qo  : (which == 1) ? Ko  : Vo;

    __shared__ ushort As[128][72];
    __shared__ ushort Bs[128][72];
    const int m0 = blockIdx.x * 128, n0 = blockIdx.y * 128;
    const int t = threadIdx.x;
    const int lane = t & 63, w = t >> 6;
    const int wr = (w >> 1) * 64, wc = (w & 1) * 64;
    const int l15 = lane & 15, l4 = lane >> 4;

    f32x4 acc[4][4] = {};
    const int sr = t >> 3, sc = (t & 7) * 8;

    for (int k0 = 0; k0 < H_; k0 += 64) {
        __syncthreads();
        #pragma unroll
        for (int p = 0; p < 4; p++) {
            uint4 av  = *(const uint4*)&X [(m0 + p * 32 + sr) * H_ + k0 + sc];
            uint4 bv2 = *(const uint4*)&Wt[(n0 + p * 32 + sr) * H_ + k0 + sc];
            *(uint4*)&As[p * 32 + sr][sc] = av;
            *(uint4*)&Bs[p * 32 + sr][sc] = bv2;
        }
        __syncthreads();
        #pragma unroll
        for (int ks = 0; ks < 2; ks++) {
            bf16x8 af[4], bfr[4];
            #pragma unroll
            for (int i = 0; i < 4; i++) af[i]  = *(const bf16x8*)&As[wr + i * 16 + l15][ks * 32 + l4 * 8];
            #pragma unroll
            for (int i = 0; i < 4; i++) bfr[i] = *(const bf16x8*)&Bs[wc + i * 16 + l15][ks * 32 + l4 * 8];
            #pragma unroll
            for (int mi = 0; mi < 4; mi++)
                #pragma unroll
                for (int ni = 0; ni < 4; ni++)
                    acc[mi][ni] = __builtin_amdgcn_mfma_f32_16x16x32_bf16(af[mi], bfr[ni], acc[mi][ni], 0, 0, 0);
        }
    }

    #pragma unroll
    for (int ni = 0; ni < 4; ni++) {
        int n = n0 + wc + ni * 16 + l15;
        float bvf = bias[n];
        int h = n >> 6, d = n & 63;
        #pragma unroll
        for (int mi = 0; mi < 4; mi++) {
            int mrow = m0 + wr + mi * 16 + l4 * 4;
            #pragma unroll
            for (int j = 0; j < 4; j++) {
                int m = mrow + j;
                int b = m >> 11, s = m & 2047;
                Out[((b * NH_ + h) * S_ + s) * HD_ + d] = f2bf(acc[mi][ni][j] + bvf);
            }
        }
    }
}

// ---------------------------------------------------------------- flash attention (split-KV)
// r10 structure (32x32 MFMA, in-reg P, reg staging, padded LDS) + 2-way kv split:
// block handles kv in [split*1024, split*1024+1024); writes UNNORMALIZED partial
// ctx^T (bf16) to Part[split] and per-q (m,l) f32 to ML[split]. Grid 2048 ->
// 8 blocks/CU = 4 waves/SIMD (2x the TLP of r10's grid-capped 2 waves/SIMD).
__global__ __launch_bounds__(128) void flash_attn(
        const ushort* __restrict__ Q, const ushort* __restrict__ K, const ushort* __restrict__ VtG,
        const float* __restrict__ maskL2, ushort* __restrict__ Part, float2* __restrict__ ML) {
    __shared__ __align__(16) ushort Ks[64][72];
    __shared__ __align__(16) ushort Vt[64][72];     // [d][kv]

    const int wgid = blockIdx.x;
    const int vid  = (wgid & 7) * 256 + (wgid >> 3);   // XCD swizzle (T1), 2048 wgs
    const int split = vid & 1;
    const int qt    = (vid >> 1) & 31;
    const int hb    = vid >> 6;           // b*NH + h
    const int b     = hb >> 4;
    const int kbase = split << 10;        // 0 or 1024

    const int t = threadIdx.x, lane = t & 63, w = t >> 6;
    const int l31 = lane & 31, hi = lane >> 5;
    const size_t head_off = (size_t)hb * S_ * HD_;
    const ushort* Qh = Q + head_off;
    const ushort* Kh = K + head_off;
    const ushort* Vh = VtG + head_off;    // [64][S]

    const int q0w  = qt * 64 + w * 32;
    const int qrow = q0w + l31;
    bf16x8 qf[4];
    #pragma unroll
    for (int kc = 0; kc < 4; kc++)
        qf[kc] = *(const bf16x8*)&Qh[qrow * 64 + kc * 16 + hi * 8];

    f32x16 acc0 = {}, acc1 = {};          // partial ctx^T (col q = l31)
    float mrun = -1e30f, lrun = 0.f;      // per-thread q = l31 (log2 domain)
    const float ksc = 0.125f * LOG2E;

    for (int kv0 = kbase; kv0 < kbase + 1024; kv0 += 64) {
        __syncthreads();
        // stage K tile + V^T tile (loads live only inside this region)
        #pragma unroll
        for (int it = 0; it < 4; it++) {
            int ci = it * 128 + t;
            int row = ci >> 3, ce = (ci & 7) * 8;
            *(uint4*)&Ks[row][ce] = *(const uint4*)&Kh[(kv0 + row) * 64 + ce];
            *(uint4*)&Vt[row][ce] = *(const uint4*)&Vh[row * S_ + kv0 + ce];
        }
        __syncthreads();

        // QK^T swapped: s0 = S^T[kv0..31][q], s1 = S^T[kv32..63][q]
        f32x16 s0 = {}, s1 = {};
        #pragma unroll
        for (int kc = 0; kc < 4; kc++) {
            bf16x8 kf0 = *(const bf16x8*)&Ks[l31][kc * 16 + hi * 8];
            bf16x8 kf1 = *(const bf16x8*)&Ks[32 + l31][kc * 16 + hi * 8];
            s0 = __builtin_amdgcn_mfma_f32_32x32x16_bf16(kf0, qf[kc], s0, 0, 0, 0);
            s1 = __builtin_amdgcn_mfma_f32_32x32x16_bf16(kf1, qf[kc], s1, 0, 0, 0);
        }

        // scale + mask (log2 domain), per-thread max over 32, 1 shfl for full kv
        float tmax = -1e30f;
        #pragma unroll
        for (int g = 0; g < 4; g++) {
            float4 mk0 = *(const float4*)&maskL2[b * S_ + kv0 + g * 8 + hi * 4];
            float4 mk1 = *(const float4*)&maskL2[b * S_ + kv0 + 32 + g * 8 + hi * 4];
            #pragma unroll
            for (int j = 0; j < 4; j++) {
                int r = g * 4 + j;
                s0[r] = fmaf(s0[r], ksc, (&mk0.x)[j]);
                s1[r] = fmaf(s1[r], ksc, (&mk1.x)[j]);
                tmax = fmaxf(tmax, fmaxf(s0[r], s1[r]));
            }
        }
        tmax = fmaxf(tmax, __shfl_xor(tmax, 32, 64));

        // defer-max (T13)
        if (!__all(tmax <= mrun + 8.0f)) {
            float mnew  = fmaxf(mrun, tmax);
            float scale = exp2f(mrun - mnew);
            mrun = mnew;
            lrun *= scale;
            #pragma unroll
            for (int r = 0; r < 16; r++) { acc0[r] *= scale; acc1[r] *= scale; }
        }

        // exp in place (constant indices -> registers), sum
        float tsum = 0.f;
        #pragma unroll
        for (int r = 0; r < 16; r++) {
            s0[r] = exp2f(s0[r] - mrun);
            s1[r] = exp2f(s1[r] - mrun);
            tsum += s0[r] + s1[r];
        }
        tsum += __shfl_xor(tsum, 32, 64);
        lrun += tsum;

        // PV B-frags, by value, no arrays
        bf16x8 pf0 = mk_pfrag(s0[0], s0[1], s0[2],  s0[3],  s0[4],  s0[5],  s0[6],  s0[7],  hi);
        bf16x8 pf1 = mk_pfrag(s0[8], s0[9], s0[10], s0[11], s0[12], s0[13], s0[14], s0[15], hi);
        bf16x8 pf2 = mk_pfrag(s1[0], s1[1], s1[2],  s1[3],  s1[4],  s1[5],  s1[6],  s1[7],  hi);
        bf16x8 pf3 = mk_pfrag(s1[8], s1[9], s1[10], s1[11], s1[12], s1[13], s1[14], s1[15], hi);

        // PV swapped: ctx^T[d][q] += V^T[d][kv] * P^T[kv][q]
        {
            bf16x8 vf0, vf1;
            vf0 = *(const bf16x8*)&Vt[l31][0 * 16 + hi * 8];
            vf1 = *(const bf16x8*)&Vt[32 + l31][0 * 16 + hi * 8];
            acc0 = __builtin_amdgcn_mfma_f32_32x32x16_bf16(vf0, pf0, acc0, 0, 0, 0);
            acc1 = __builtin_amdgcn_mfma_f32_32x32x16_bf16(vf1, pf0, acc1, 0, 0, 0);
            vf0 = *(const bf16x8*)&Vt[l31][1 * 16 + hi * 8];
            vf1 = *(const bf16x8*)&Vt[32 + l31][1 * 16 + hi * 8];
            acc0 = __builtin_amdgcn_mfma_f32_32x32x16_bf16(vf0, pf1, acc0, 0, 0, 0);
            acc1 = __builtin_amdgcn_mfma_f32_32x32x16_bf16(vf1, pf1, acc1, 0, 0, 0);
            vf0 = *(const bf16x8*)&Vt[l31][2 * 16 + hi * 8];
            vf1 = *(const bf16x8*)&Vt[32 + l31][2 * 16 + hi * 8];
            acc0 = __builtin_amdgcn_mfma_f32_32x32x16_bf16(vf0, pf2, acc0, 0, 0, 0);
            acc1 = __builtin_amdgcn_mfma_f32_32x32x16_bf16(vf1, pf2, acc1, 0, 0, 0);
            vf0 = *(const bf16x8*)&Vt[l31][3 * 16 + hi * 8];
            vf1 = *(const bf16x8*)&Vt[32 + l31][3 * 16 + hi * 8];
            acc0 = __builtin_amdgcn_mfma_f32_32x32x16_bf16(vf0, pf3, acc0, 0, 0, 0);
            acc1 = __builtin_amdgcn_mfma_f32_32x32x16_bf16(vf1, pf3, acc1, 0, 0, 0);
        }
    }

    // epilogue: write UNNORMALIZED partial (bf16) + (m,l)
    ushort* Pp = Part + (size_t)split * (B_ * S_ * H_);
    const int h = hb & (NH_ - 1);
    const size_t rowbase = ((size_t)b * S_ + q0w + l31) * H_ + h * 64;
    #pragma unroll
    for (int g = 0; g < 4; g++) {
        ushort4 o0, o1;
        o0.x = f2bf(acc0[g * 4 + 0]); o0.y = f2bf(acc0[g * 4 + 1]);
        o0.z = f2bf(acc0[g * 4 + 2]); o0.w = f2bf(acc0[g * 4 + 3]);
        o1.x = f2bf(acc1[g * 4 + 0]); o1.y = f2bf(acc1[g * 4 + 1]);
        o1.z = f2bf(acc1[g * 4 + 2]); o1.w = f2bf(acc1[g * 4 + 3]);
        *(ushort4*)&Pp[rowbase + g * 8 + hi * 4]      = o0;
        *(ushort4*)&Pp[rowbase + 32 + g * 8 + hi * 4] = o1;
    }
    if (hi == 0)
        ML[(size_t)split * (B_ * NH_ * S_) + (size_t)hb * S_ + q0w + l31] = make_float2(mrun, lrun);
}

// ---------------------------------------------------------------- split-KV combine
// ctx = (P0*e0 + P1*e1) / (l0*e0 + l1*e1), e_i = 2^(m_i - M)
__global__ __launch_bounds__(256) void combine_kv(
        const ushort* __restrict__ P0, const ushort* __restrict__ P1,
        const float2* __restrict__ ML0, const float2* __restrict__ ML1,
        ushort* __restrict__ ctx) {
    const int row = blockIdx.x;           // b*S + s
    const int t = threadIdx.x;
    const int b = row >> 11, s = row & 2047;
    const int col = t * 4;
    const int h = col >> 6;
    const int hb = b * NH_ + h;

    float2 a = ML0[(size_t)hb * S_ + s];
    float2 c = ML1[(size_t)hb * S_ + s];
    float M  = fmaxf(a.x, c.x);
    float e0 = exp2f(a.x - M), e1 = exp2f(c.x - M);
    float inv = 1.0f / (a.y * e0 + c.y * e1);

    ushort4 p0 = *(const ushort4*)&P0[(size_t)row * H_ + col];
    ushort4 p1 = *(const ushort4*)&P1[(size_t)row * H_ + col];
    ushort4 o;
    o.x = f2bf((bf2f(p0.x) * e0 + bf2f(p1.x) * e1) * inv);
    o.y = f2bf((bf2f(p0.y) * e0 + bf2f(p1.y) * e1) * inv);
    o.z = f2bf((bf2f(p0.z) * e0 + bf2f(p1.z) * e1) * inv);
    o.w = f2bf((bf2f(p0.w) * e0 + bf2f(p1.w) * e1) * inv);
    *(ushort4*)&ctx[(size_t)row * H_ + col] = o;
}

// ---------------------------------------------------------------- out proj + residual
__global__ __launch_bounds__(256) void out_proj(
        const ushort* __restrict__ Ctx, const ushort* __restrict__ Wot,
        const float* __restrict__ bo,  const float* __restrict__ Hs,
        float* __restrict__ Tmp) {
    __shared__ ushort As[128][72];
    __shared__ ushort Bs[128][72];
    const int m0 = blockIdx.x * 128, n0 = blockIdx.y * 128;
    const int t = threadIdx.x;
    const int lane = t & 63, w = t >> 6;
    const int wr = (w >> 1) * 64, wc = (w & 1) * 64;
    const int l15 = lane & 15, l4 = lane >> 4;

    f32x4 acc[4][4] = {};
    const int sr = t >> 3, sc = (t & 7) * 8;

    for (int k0 = 0; k0 < H_; k0 += 64) {
        __syncthreads();
        #pragma unroll
        for (int p = 0; p < 4; p++) {
            uint4 av  = *(const uint4*)&Ctx[(m0 + p * 32 + sr) * H_ + k0 + sc];
            uint4 bv2 = *(const uint4*)&Wot[(n0 + p * 32 + sr) * H_ + k0 + sc];
            *(uint4*)&As[p * 32 + sr][sc] = av;
            *(uint4*)&Bs[p * 32 + sr][sc] = bv2;
        }
        __syncthreads();
        #pragma unroll
        for (int ks = 0; ks < 2; ks++) {
            bf16x8 af[4], bfr[4];
            #pragma unroll
            for (int i = 0; i < 4; i++) af[i]  = *(const bf16x8*)&As[wr + i * 16 + l15][ks * 32 + l4 * 8];
            #pragma unroll
            for (int i = 0; i < 4; i++) bfr[i] = *(const bf16x8*)&Bs[wc + i * 16 + l15][ks * 32 + l4 * 8];
            #pragma unroll
            for (int mi = 0; mi < 4; mi++)
                #pragma unroll
                for (int ni = 0; ni < 4; ni++)
                    acc[mi][ni] = __builtin_amdgcn_mfma_f32_16x16x32_bf16(af[mi], bfr[ni], acc[mi][ni], 0, 0, 0);
        }
    }

    #pragma unroll
    for (int ni = 0; ni < 4; ni++) {
        int n = n0 + wc + ni * 16 + l15;
        float bvf = bo[n];
        #pragma unroll
        for (int mi = 0; mi < 4; mi++) {
            int mrow = m0 + wr + mi * 16 + l4 * 4;
            #pragma unroll
            for (int j = 0; j < 4; j++) {
                int m = mrow + j;
                Tmp[(size_t)m * H_ + n] = acc[mi][ni][j] + bvf + Hs[(size_t)m * H_ + n];
            }
        }
    }
}

// ---------------------------------------------------------------- layernorm (fp32 out)
__global__ __launch_bounds__(256) void ln_kernel(
        const float* __restrict__ Tmp, const float* __restrict__ gamma,
        const float* __restrict__ beta, float* __restrict__ Out) {
    const int row = blockIdx.x;
    const float* x = Tmp + (size_t)row * H_;
    const int t = threadIdx.x, w = t >> 6, lane = t & 63;

    float4 v = *(const float4*)&x[t * 4];
    float s = v.x + v.y + v.z + v.w;
    #pragma unroll
    for (int m = 1; m < 64; m <<= 1) s += __shfl_xor(s, m, 64);
    __shared__ float red[4], red2[4];
    if (lane == 0) red[w] = s;
    __syncthreads();
    float mu = (red[0] + red[1] + red[2] + red[3]) * (1.0f / H_);

    float d0 = v.x - mu, d1 = v.y - mu, d2 = v.z - mu, d3 = v.w - mu;
    float sq = d0 * d0 + d1 * d1 + d2 * d2 + d3 * d3;
    #pragma unroll
    for (int m = 1; m < 64; m <<= 1) sq += __shfl_xor(sq, m, 64);
    if (lane == 0) red2[w] = sq;
    __syncthreads();
    float var = (red2[0] + red2[1] + red2[2] + red2[3]) * (1.0f / H_);
    float rstd = rsqrtf(var + EPSLN);

    float dd[4] = {d0, d1, d2, d3};
    float4 o;
    o.x = dd[0] * rstd * gamma[t * 4 + 0] + beta[t * 4 + 0];
    o.y = dd[1] * rstd * gamma[t * 4 + 1] + beta[t * 4 + 1];
    o.z = dd[2] * rstd * gamma[t * 4 + 2] + beta[t * 4 + 2];
    o.w = dd[3] * rstd * gamma[t * 4 + 3] + beta[t * 4 + 3];
    *(float4*)&Out[(size_t)row * H_ + t * 4] = o;
}

// ---------------------------------------------------------------- launch
extern "C" void kernel_launch(void* const* d_in, const int* in_sizes, int n_in,
                              void* d_out, int out_size, void* d_ws, size_t ws_size,
                              hipStream_t stream) {
    const float* hs    = (const float*)d_in[0];
    const float* mask  = (const float*)d_in[1];
    const float* Wq    = (const float*)d_in[2];
    const float* bq    = (const float*)d_in[3];
    const float* Wk    = (const float*)d_in[4];
    const float* bk    = (const float*)d_in[5];
    const float* Wv    = (const float*)d_in[6];
    const float* bv    = (const float*)d_in[7];
    const float* Wo    = (const float*)d_in[8];
    const float* bo    = (const float*)d_in[9];
    const float* gamma = (const float*)d_in[10];
    const float* beta  = (const float*)d_in[11];

    char* ws = (char*)d_ws;
    const size_t WSZ = (size_t)H_ * H_;           // 1M elems
    const size_t TSZ = (size_t)B_ * S_ * H_;      // 4M elems
    ushort* Wqt = (ushort*)ws;
    ushort* Wkt = Wqt + WSZ;
    ushort* Wvt = Wkt + WSZ;
    ushort* Wot = Wvt + WSZ;
    ushort* Xb  = Wot + WSZ;
    ushort* Qb  = Xb + TSZ;
    ushort* Kb  = Qb + TSZ;
    ushort* Vb  = Kb + TSZ;
    ushort* Ctx = Vb + TSZ;
    float*  Tmp = (float*)(Ctx + TSZ);
    // aliases into dead regions (all within the original 64 MB):
    float*  MaskL2 = (float*)Wqt;          // Wqt dead after qkv_gemm (16 KB used)
    float2* ML     = (float2*)Wkt;         // Wkt dead after qkv_gemm (1 MB used)
    ushort* VtG    = Xb;                   // Xb dead after qkv_gemm (8 MB)
    ushort* Part   = (ushort*)Tmp;         // Tmp region: Part0+Part1 = 16 MB;
                                           // dead before out_proj writes Tmp

    cvt_f32_bf16<<<TSZ / (256 * 4), 256, 0, stream>>>(hs, Xb, (int)TSZ);
    transpose_cvt<<<dim3(16, 16, 4), 256, 0, stream>>>(Wq, Wk, Wv, Wo, Wqt, Wkt, Wvt, Wot);

    qkv_gemm<<<dim3(32, 8, 3), 256, 0, stream>>>(Xb, Wqt, Wkt, Wvt, bq, bk, bv, Qb, Kb, Vb);
    scale_mask<<<(B_ * S_) / 256, 256, 0, stream>>>(mask, MaskL2);
    v_transpose<<<dim3(S_ / 64, B_ * NH_), 256, 0, stream>>>(Vb, VtG);
    flash_attn<<<dim3(2048), 128, 0, stream>>>(Qb, Kb, VtG, MaskL2, Part, ML);
    combine_kv<<<dim3(B_ * S_), 256, 0, stream>>>(Part, Part + TSZ,
                                                  ML, ML + (size_t)B_ * NH_ * S_, Ctx);
    out_proj<<<dim3(32, 8), 256, 0, stream>>>(Ctx, Wot, bo, hs, Tmp);
    ln_kernel<<<B_ * S_, 256, 0, stream>>>(Tmp, gamma, beta, (float*)d_out);
}

// Round 13
// 169.212 us; speedup vs baseline: 1.1839x; 1.1839x over previous
//
#include <hip/hip_runtime.h>
#include <hip/hip_bf16.h>

#define B_  2
#define S_  2048
#define H_  1024
#define NH_ 16
#define HD_ 64
#define EPSLN 1e-12f
#define LOG2E 1.4426950408889634f

typedef short bf16x8 __attribute__((ext_vector_type(8)));
typedef float f32x4  __attribute__((ext_vector_type(4)));
typedef float f32x16 __attribute__((ext_vector_type(16)));
typedef unsigned int u32x4 __attribute__((ext_vector_type(4)));

__device__ __forceinline__ float bf2f(ushort u) {
    union { unsigned int i; float f; } v; v.i = ((unsigned int)u) << 16; return v.f;
}
__device__ __forceinline__ ushort f2bf(float f) {
    union { float f; unsigned int i; } v; v.f = f;
    unsigned int r = v.i + 0x7FFFu + ((v.i >> 16) & 1u);   // RNE
    return (ushort)(r >> 16);
}
__device__ __forceinline__ ushort f2bf_hw(float f) {
    __hip_bfloat16 h = __float2bfloat16(f);
    return *reinterpret_cast<ushort*>(&h);
}
__device__ __forceinline__ unsigned int pack_bf2(float a, float b) {
    return ((unsigned int)f2bf_hw(b) << 16) | (unsigned int)f2bf_hw(a);
}

// async global->LDS, 16B per lane; LDS dest = wave-uniform base + lane*16
// (correctness proven in r11's passing run)
__device__ __forceinline__ void gll16(const ushort* g, ushort* l) {
    __builtin_amdgcn_global_load_lds((const __attribute__((address_space(1))) void*)g,
                                     (__attribute__((address_space(3))) void*)l, 16, 0, 0);
}

// build one PV B-frag from 8 exp values (all by value -> registers only)
__device__ __forceinline__ bf16x8 mk_pfrag(float a0, float a1, float a2, float a3,
                                           float a4, float a5, float a6, float a7, int hi) {
    unsigned int Lo0 = pack_bf2(a0, a1);
    unsigned int Lo1 = pack_bf2(a2, a3);
    unsigned int Hi0 = pack_bf2(a4, a5);
    unsigned int Hi1 = pack_bf2(a6, a7);
    unsigned int sLo0 = (unsigned int)__shfl_xor((int)Lo0, 32, 64);
    unsigned int sLo1 = (unsigned int)__shfl_xor((int)Lo1, 32, 64);
    unsigned int sHi0 = (unsigned int)__shfl_xor((int)Hi0, 32, 64);
    unsigned int sHi1 = (unsigned int)__shfl_xor((int)Hi1, 32, 64);
    u32x4 d;
    d.x = hi ? sHi0 : Lo0;
    d.y = hi ? sHi1 : Lo1;
    d.z = hi ? Hi0 : sLo0;
    d.w = hi ? Hi1 : sLo1;
    return __builtin_bit_cast(bf16x8, d);
}

// ---------------------------------------------------------------- fp32 -> bf16 convert
__global__ __launch_bounds__(256) void cvt_f32_bf16(const float* __restrict__ in,
                                                    ushort* __restrict__ out, int n) {
    int i = (blockIdx.x * 256 + threadIdx.x) * 4;
    float4 v = *(const float4*)&in[i];
    ushort4 o = make_ushort4(f2bf(v.x), f2bf(v.y), f2bf(v.z), f2bf(v.w));
    *(ushort4*)&out[i] = o;
}

// ---------------------------------------------------------------- mask * log2(e)
__global__ __launch_bounds__(256) void scale_mask(const float* __restrict__ in,
                                                  float* __restrict__ out) {
    int i = blockIdx.x * 256 + threadIdx.x;
    out[i] = in[i] * LOG2E;
}

// ---------------------------------------------------------------- transpose + convert
__global__ __launch_bounds__(256) void transpose_cvt(
        const float* __restrict__ W0, const float* __restrict__ W1,
        const float* __restrict__ W2, const float* __restrict__ W3,
        ushort* __restrict__ T0, ushort* __restrict__ T1,
        ushort* __restrict__ T2, ushort* __restrict__ T3) {
    const int z = blockIdx.z;
    const float* in = (z == 0) ? W0 : (z == 1) ? W1 : (z == 2) ? W2 : W3;
    ushort* out     = (z == 0) ? T0 : (z == 1) ? T1 : (z == 2) ? T2 : T3;

    __shared__ float tile[64][65];
    const int bx = blockIdx.x * 64, by = blockIdx.y * 64;
    const int t = threadIdx.x;
    #pragma unroll
    for (int i = 0; i < 16; i++) {
        int idx = t + i * 256;
        int r = idx >> 6, c = idx & 63;
        tile[r][c] = in[(by + r) * 1024 + bx + c];
    }
    __syncthreads();
    #pragma unroll
    for (int i = 0; i < 16; i++) {
        int idx = t + i * 256;
        int r = idx >> 6, c = idx & 63;
        out[(bx + r) * 1024 + by + c] = f2bf(tile[c][r]);
    }
}

// ---------------------------------------------------------------- V transpose (bf16)
__global__ __launch_bounds__(256) void v_transpose(const ushort* __restrict__ Vb,
                                                   ushort* __restrict__ VtG) {
    __shared__ ushort tile[64][72];
    const int s0 = blockIdx.x * 64;
    const int head = blockIdx.y;
    const ushort* src = Vb + (size_t)head * S_ * HD_;
    ushort* dst       = VtG + (size_t)head * S_ * HD_;
    const int t = threadIdx.x, lane = t & 63, w = t >> 6;

    uint4 a = *(const uint4*)&src[(s0 + lane) * HD_ + w * 16];
    uint4 b = *(const uint4*)&src[(s0 + lane) * HD_ + w * 16 + 8];
    const ushort* pa = (const ushort*)&a;
    #pragma unroll
    for (int i = 0; i < 8; i++) tile[w * 16 + i][lane] = pa[i];
    const ushort* pb = (const ushort*)&b;
    #pragma unroll
    for (int i = 0; i < 8; i++) tile[w * 16 + 8 + i][lane] = pb[i];
    __syncthreads();

    const int d = t >> 2, sc = (t & 3) * 16;
    uint4 o1 = *(const uint4*)&tile[d][sc];
    uint4 o2 = *(const uint4*)&tile[d][sc + 8];
    *(uint4*)&dst[d * S_ + s0 + sc]     = o1;
    *(uint4*)&dst[d * S_ + s0 + sc + 8] = o2;
}

// ---------------------------------------------------------------- QKV GEMM (m97 staging)
// 128x128 tile, BK=64, global_load_lds width-16 into LINEAR LDS [128*64].
__global__ __launch_bounds__(256) void qkv_gemm(
        const ushort* __restrict__ X,
        const ushort* __restrict__ Wqt, const ushort* __restrict__ Wkt, const ushort* __restrict__ Wvt,
        const float* __restrict__ bq,  const float* __restrict__ bk,  const float* __restrict__ bv,
        ushort* __restrict__ Qo, ushort* __restrict__ Ko, ushort* __restrict__ Vo) {
    const int which = blockIdx.z;
    const ushort* Wt  = (which == 0) ? Wqt : (which == 1) ? Wkt : Wvt;
    const float* bias = (which == 0) ? bq  : (which == 1) ? bk  : bv;
    ushort* Out       = (which == 0) ? Qo  : (which == 1) ? Ko  : Vo;

    __shared__ __align__(16) ushort As[128 * 64];
    __shared__ __align__(16) ushort Bs[128 * 64];
    const int m0 = blockIdx.x * 128, n0 = blockIdx.y * 128;
    const int t = threadIdx.x;
    const int lane = t & 63, w = t >> 6;
    const int wr = (w >> 1) * 64, wc = (w & 1) * 64;
    const int l15 = lane & 15, l4 = lane >> 4;

    f32x4 acc[4][4] = {};

    for (int k0 = 0; k0 < H_; k0 += 64) {
        // stage via global_load_lds: chunk ci = it*256 + t -> row=ci>>3, col=(ci&7)*8
        #pragma unroll
        for (int it = 0; it < 4; it++) {
            int ci = it * 256 + t;
            int row = ci >> 3, col = (ci & 7) * 8;
            gll16(&X [(m0 + row) * H_ + k0 + col], &As[ci * 8]);
            gll16(&Wt[(n0 + row) * H_ + k0 + col], &Bs[ci * 8]);
        }
        __syncthreads();   // drains vmcnt -> tiles resident
        #pragma unroll
        for (int ks = 0; ks < 2; ks++) {
            bf16x8 af[4], bfr[4];
            #pragma unroll
            for (int i = 0; i < 4; i++) af[i]  = *(const bf16x8*)&As[(wr + i * 16 + l15) * 64 + ks * 32 + l4 * 8];
            #pragma unroll
            for (int i = 0; i < 4; i++) bfr[i] = *(const bf16x8*)&Bs[(wc + i * 16 + l15) * 64 + ks * 32 + l4 * 8];
            #pragma unroll
            for (int mi = 0; mi < 4; mi++)
                #pragma unroll
                for (int ni = 0; ni < 4; ni++)
                    acc[mi][ni] = __builtin_amdgcn_mfma_f32_16x16x32_bf16(af[mi], bfr[ni], acc[mi][ni], 0, 0, 0);
        }
        __syncthreads();   // all reads done before next overwrite
    }

    #pragma unroll
    for (int ni = 0; ni < 4; ni++) {
        int n = n0 + wc + ni * 16 + l15;
        float bvf = bias[n];
        int h = n >> 6, d = n & 63;
        #pragma unroll
        for (int mi = 0; mi < 4; mi++) {
            int mrow = m0 + wr + mi * 16 + l4 * 4;
            #pragma unroll
            for (int j = 0; j < 4; j++) {
                int m = mrow + j;
                int b = m >> 11, s = m & 2047;
                Out[((b * NH_ + h) * S_ + s) * HD_ + d] = f2bf(acc[mi][ni][j] + bvf);
            }
        }
    }
}

// ---------------------------------------------------------------- flash attention
// r10 structure (32x32 MFMA, in-reg P, reg staging, padded LDS), now 4 waves/block
// with QBLK=128: K/V staging + barriers amortize over 2x the q-rows. Grid 512.
__global__ __launch_bounds__(256) void flash_attn(
        const ushort* __restrict__ Q, const ushort* __restrict__ K, const ushort* __restrict__ VtG,
        const float* __restrict__ maskL2, ushort* __restrict__ ctx) {
    __shared__ __align__(16) ushort Ks[64][72];
    __shared__ __align__(16) ushort Vt[64][72];     // [d][kv]

    const int wgid = blockIdx.x;
    const int vid  = (wgid & 7) * 64 + (wgid >> 3);   // XCD swizzle (T1), 512 wgs
    const int qt   = vid & 15;
    const int hb   = vid >> 4;            // b*NH + h
    const int h    = hb & (NH_ - 1), b = hb >> 4;

    const int t = threadIdx.x, lane = t & 63, w = t >> 6;   // w = 0..3
    const int l31 = lane & 31, hi = lane >> 5;
    const size_t head_off = (size_t)hb * S_ * HD_;
    const ushort* Qh = Q + head_off;
    const ushort* Kh = K + head_off;
    const ushort* Vh = VtG + head_off;    // [64][S]

    const int q0w  = qt * 128 + w * 32;
    const int qrow = q0w + l31;
    bf16x8 qf[4];
    #pragma unroll
    for (int kc = 0; kc < 4; kc++)
        qf[kc] = *(const bf16x8*)&Qh[qrow * 64 + kc * 16 + hi * 8];

    f32x16 acc0 = {}, acc1 = {};          // ctx^T: d-halves 0-31, 32-63 (col q = l31)
    float mrun = -1e30f, lrun = 0.f;      // per-thread q = l31 (log2 domain)
    const float ksc = 0.125f * LOG2E;

    for (int kv0 = 0; kv0 < S_; kv0 += 64) {
        __syncthreads();
        // stage K tile + V^T tile: 512 chunks of 8 elems across 256 threads
        #pragma unroll
        for (int it = 0; it < 2; it++) {
            int ci = it * 256 + t;
            int row = ci >> 3, ce = (ci & 7) * 8;
            *(uint4*)&Ks[row][ce] = *(const uint4*)&Kh[(kv0 + row) * 64 + ce];
            *(uint4*)&Vt[row][ce] = *(const uint4*)&Vh[row * S_ + kv0 + ce];
        }
        __syncthreads();

        // QK^T swapped: s0 = S^T[kv0..31][q], s1 = S^T[kv32..63][q]
        f32x16 s0 = {}, s1 = {};
        #pragma unroll
        for (int kc = 0; kc < 4; kc++) {
            bf16x8 kf0 = *(const bf16x8*)&Ks[l31][kc * 16 + hi * 8];
            bf16x8 kf1 = *(const bf16x8*)&Ks[32 + l31][kc * 16 + hi * 8];
            s0 = __builtin_amdgcn_mfma_f32_32x32x16_bf16(kf0, qf[kc], s0, 0, 0, 0);
            s1 = __builtin_amdgcn_mfma_f32_32x32x16_bf16(kf1, qf[kc], s1, 0, 0, 0);
        }

        // scale + mask (log2 domain), per-thread max over 32, 1 shfl for full kv
        float tmax = -1e30f;
        #pragma unroll
        for (int g = 0; g < 4; g++) {
            float4 mk0 = *(const float4*)&maskL2[b * S_ + kv0 + g * 8 + hi * 4];
            float4 mk1 = *(const float4*)&maskL2[b * S_ + kv0 + 32 + g * 8 + hi * 4];
            #pragma unroll
            for (int j = 0; j < 4; j++) {
                int r = g * 4 + j;
                s0[r] = fmaf(s0[r], ksc, (&mk0.x)[j]);
                s1[r] = fmaf(s1[r], ksc, (&mk1.x)[j]);
                tmax = fmaxf(tmax, fmaxf(s0[r], s1[r]));
            }
        }
        tmax = fmaxf(tmax, __shfl_xor(tmax, 32, 64));

        // defer-max (T13)
        if (!__all(tmax <= mrun + 8.0f)) {
            float mnew  = fmaxf(mrun, tmax);
            float scale = exp2f(mrun - mnew);
            mrun = mnew;
            lrun *= scale;
            #pragma unroll
            for (int r = 0; r < 16; r++) { acc0[r] *= scale; acc1[r] *= scale; }
        }

        // exp in place (constant indices -> registers), sum
        float tsum = 0.f;
        #pragma unroll
        for (int r = 0; r < 16; r++) {
            s0[r] = exp2f(s0[r] - mrun);
            s1[r] = exp2f(s1[r] - mrun);
            tsum += s0[r] + s1[r];
        }
        tsum += __shfl_xor(tsum, 32, 64);
        lrun += tsum;

        // PV B-frags, by value, no arrays
        bf16x8 pf0 = mk_pfrag(s0[0], s0[1], s0[2],  s0[3],  s0[4],  s0[5],  s0[6],  s0[7],  hi);
        bf16x8 pf1 = mk_pfrag(s0[8], s0[9], s0[10], s0[11], s0[12], s0[13], s0[14], s0[15], hi);
        bf16x8 pf2 = mk_pfrag(s1[0], s1[1], s1[2],  s1[3],  s1[4],  s1[5],  s1[6],  s1[7],  hi);
        bf16x8 pf3 = mk_pfrag(s1[8], s1[9], s1[10], s1[11], s1[12], s1[13], s1[14], s1[15], hi);

        // PV swapped: ctx^T[d][q] += V^T[d][kv] * P^T[kv][q]
        {
            bf16x8 vf0, vf1;
            vf0 = *(const bf16x8*)&Vt[l31][0 * 16 + hi * 8];
            vf1 = *(const bf16x8*)&Vt[32 + l31][0 * 16 + hi * 8];
            acc0 = __builtin_amdgcn_mfma_f32_32x32x16_bf16(vf0, pf0, acc0, 0, 0, 0);
            acc1 = __builtin_amdgcn_mfma_f32_32x32x16_bf16(vf1, pf0, acc1, 0, 0, 0);
            vf0 = *(const bf16x8*)&Vt[l31][1 * 16 + hi * 8];
            vf1 = *(const bf16x8*)&Vt[32 + l31][1 * 16 + hi * 8];
            acc0 = __builtin_amdgcn_mfma_f32_32x32x16_bf16(vf0, pf1, acc0, 0, 0, 0);
            acc1 = __builtin_amdgcn_mfma_f32_32x32x16_bf16(vf1, pf1, acc1, 0, 0, 0);
            vf0 = *(const bf16x8*)&Vt[l31][2 * 16 + hi * 8];
            vf1 = *(const bf16x8*)&Vt[32 + l31][2 * 16 + hi * 8];
            acc0 = __builtin_amdgcn_mfma_f32_32x32x16_bf16(vf0, pf2, acc0, 0, 0, 0);
            acc1 = __builtin_amdgcn_mfma_f32_32x32x16_bf16(vf1, pf2, acc1, 0, 0, 0);
            vf0 = *(const bf16x8*)&Vt[l31][3 * 16 + hi * 8];
            vf1 = *(const bf16x8*)&Vt[32 + l31][3 * 16 + hi * 8];
            acc0 = __builtin_amdgcn_mfma_f32_32x32x16_bf16(vf0, pf3, acc0, 0, 0, 0);
            acc1 = __builtin_amdgcn_mfma_f32_32x32x16_bf16(vf1, pf3, acc1, 0, 0, 0);
        }
    }

    // epilogue: d = dh*32 + g*8 + hi*4 + j, s = q0w + l31
    const float inv = 1.0f / lrun;
    const size_t rowbase = ((size_t)b * S_ + q0w + l31) * H_ + h * 64;
    #pragma unroll
    for (int g = 0; g < 4; g++) {
        ushort4 o0, o1;
        o0.x = f2bf(acc0[g * 4 + 0] * inv); o0.y = f2bf(acc0[g * 4 + 1] * inv);
        o0.z = f2bf(acc0[g * 4 + 2] * inv); o0.w = f2bf(acc0[g * 4 + 3] * inv);
        o1.x = f2bf(acc1[g * 4 + 0] * inv); o1.y = f2bf(acc1[g * 4 + 1] * inv);
        o1.z = f2bf(acc1[g * 4 + 2] * inv); o1.w = f2bf(acc1[g * 4 + 3] * inv);
        *(ushort4*)&ctx[rowbase + g * 8 + hi * 4]      = o0;
        *(ushort4*)&ctx[rowbase + 32 + g * 8 + hi * 4] = o1;
    }
}

// ---------------------------------------------------------------- out proj + residual (m97 staging)
__global__ __launch_bounds__(256) void out_proj(
        const ushort* __restrict__ Ctx, const ushort* __restrict__ Wot,
        const float* __restrict__ bo,  const float* __restrict__ Hs,
        float* __restrict__ Tmp) {
    __shared__ __align__(16) ushort As[128 * 64];
    __shared__ __align__(16) ushort Bs[128 * 64];
    const int m0 = blockIdx.x * 128, n0 = blockIdx.y * 128;
    const int t = threadIdx.x;
    const int lane = t & 63, w = t >> 6;
    const int wr = (w >> 1) * 64, wc = (w & 1) * 64;
    const int l15 = lane & 15, l4 = lane >> 4;

    f32x4 acc[4][4] = {};

    for (int k0 = 0; k0 < H_; k0 += 64) {
        #pragma unroll
        for (int it = 0; it < 4; it++) {
            int ci = it * 256 + t;
            int row = ci >> 3, col = (ci & 7) * 8;
            gll16(&Ctx[(m0 + row) * H_ + k0 + col], &As[ci * 8]);
            gll16(&Wot[(n0 + row) * H_ + k0 + col], &Bs[ci * 8]);
        }
        __syncthreads();
        #pragma unroll
        for (int ks = 0; ks < 2; ks++) {
            bf16x8 af[4], bfr[4];
            #pragma unroll
            for (int i = 0; i < 4; i++) af[i]  = *(const bf16x8*)&As[(wr + i * 16 + l15) * 64 + ks * 32 + l4 * 8];
            #pragma unroll
            for (int i = 0; i < 4; i++) bfr[i] = *(const bf16x8*)&Bs[(wc + i * 16 + l15) * 64 + ks * 32 + l4 * 8];
            #pragma unroll
            for (int mi = 0; mi < 4; mi++)
                #pragma unroll
                for (int ni = 0; ni < 4; ni++)
                    acc[mi][ni] = __builtin_amdgcn_mfma_f32_16x16x32_bf16(af[mi], bfr[ni], acc[mi][ni], 0, 0, 0);
        }
        __syncthreads();
    }

    #pragma unroll
    for (int ni = 0; ni < 4; ni++) {
        int n = n0 + wc + ni * 16 + l15;
        float bvf = bo[n];
        #pragma unroll
        for (int mi = 0; mi < 4; mi++) {
            int mrow = m0 + wr + mi * 16 + l4 * 4;
            #pragma unroll
            for (int j = 0; j < 4; j++) {
                int m = mrow + j;
                Tmp[(size_t)m * H_ + n] = acc[mi][ni][j] + bvf + Hs[(size_t)m * H_ + n];
            }
        }
    }
}

// ---------------------------------------------------------------- layernorm (fp32 out)
__global__ __launch_bounds__(256) void ln_kernel(
        const float* __restrict__ Tmp, const float* __restrict__ gamma,
        const float* __restrict__ beta, float* __restrict__ Out) {
    const int row = blockIdx.x;
    const float* x = Tmp + (size_t)row * H_;
    const int t = threadIdx.x, w = t >> 6, lane = t & 63;

    float4 v = *(const float4*)&x[t * 4];
    float s = v.x + v.y + v.z + v.w;
    #pragma unroll
    for (int m = 1; m < 64; m <<= 1) s += __shfl_xor(s, m, 64);
    __shared__ float red[4], red2[4];
    if (lane == 0) red[w] = s;
    __syncthreads();
    float mu = (red[0] + red[1] + red[2] + red[3]) * (1.0f / H_);

    float d0 = v.x - mu, d1 = v.y - mu, d2 = v.z - mu, d3 = v.w - mu;
    float sq = d0 * d0 + d1 * d1 + d2 * d2 + d3 * d3;
    #pragma unroll
    for (int m = 1; m < 64; m <<= 1) sq += __shfl_xor(sq, m, 64);
    if (lane == 0) red2[w] = sq;
    __syncthreads();
    float var = (red2[0] + red2[1] + red2[2] + red2[3]) * (1.0f / H_);
    float rstd = rsqrtf(var + EPSLN);

    float dd[4] = {d0, d1, d2, d3};
    float4 o;
    o.x = dd[0] * rstd * gamma[t * 4 + 0] + beta[t * 4 + 0];
    o.y = dd[1] * rstd * gamma[t * 4 + 1] + beta[t * 4 + 1];
    o.z = dd[2] * rstd * gamma[t * 4 + 2] + beta[t * 4 + 2];
    o.w = dd[3] * rstd * gamma[t * 4 + 3] + beta[t * 4 + 3];
    *(float4*)&Out[(size_t)row * H_ + t * 4] = o;
}

// ---------------------------------------------------------------- launch
extern "C" void kernel_launch(void* const* d_in, const int* in_sizes, int n_in,
                              void* d_out, int out_size, void* d_ws, size_t ws_size,
                              hipStream_t stream) {
    const float* hs    = (const float*)d_in[0];
    const float* mask  = (const float*)d_in[1];
    const float* Wq    = (const float*)d_in[2];
    const float* bq    = (const float*)d_in[3];
    const float* Wk    = (const float*)d_in[4];
    const float* bk    = (const float*)d_in[5];
    const float* Wv    = (const float*)d_in[6];
    const float* bv    = (const float*)d_in[7];
    const float* Wo    = (const float*)d_in[8];
    const float* bo    = (const float*)d_in[9];
    const float* gamma = (const float*)d_in[10];
    const float* beta  = (const float*)d_in[11];

    char* ws = (char*)d_ws;
    const size_t WSZ = (size_t)H_ * H_;           // 1M elems
    const size_t TSZ = (size_t)B_ * S_ * H_;      // 4M elems
    ushort* Wqt = (ushort*)ws;
    ushort* Wkt = Wqt + WSZ;
    ushort* Wvt = Wkt + WSZ;
    ushort* Wot = Wvt + WSZ;
    ushort* Xb  = Wot + WSZ;
    ushort* Qb  = Xb + TSZ;
    ushort* Kb  = Qb + TSZ;
    ushort* Vb  = Kb + TSZ;
    ushort* Ctx = Vb + TSZ;
    float*  Tmp = (float*)(Ctx + TSZ);
    ushort* VtG = (ushort*)Tmp;       // alias: dead before out_proj writes Tmp
    float* MaskL2 = (float*)Xb;       // alias: Xb dead after qkv_gemm

    cvt_f32_bf16<<<TSZ / (256 * 4), 256, 0, stream>>>(hs, Xb, (int)TSZ);
    transpose_cvt<<<dim3(16, 16, 4), 256, 0, stream>>>(Wq, Wk, Wv, Wo, Wqt, Wkt, Wvt, Wot);

    qkv_gemm<<<dim3(32, 8, 3), 256, 0, stream>>>(Xb, Wqt, Wkt, Wvt, bq, bk, bv, Qb, Kb, Vb);
    scale_mask<<<(B_ * S_) / 256, 256, 0, stream>>>(mask, MaskL2);
    v_transpose<<<dim3(S_ / 64, B_ * NH_), 256, 0, stream>>>(Vb, VtG);
    flash_attn<<<dim3(512), 256, 0, stream>>>(Qb, Kb, VtG, MaskL2, Ctx);
    out_proj<<<dim3(32, 8), 256, 0, stream>>>(Ctx, Wot, bo, hs, Tmp);
    ln_kernel<<<B_ * S_, 256, 0, stream>>>(Tmp, gamma, beta, (float*)d_out);
}